// Round 10
// baseline (388.168 us; speedup 1.0000x reference)
//
#include <hip/hip_runtime.h>

#define N_NODES 100000
#define N_EDGES 3200000
#define F_IN 128
#define F_OUT 16

#define NSEG 1024                // binning segments
#define EPS (N_EDGES / NSEG)     // 3125 edges/segment (exact)
#define EPT 7                    // max edges per thread (ceil(3125/512))
#define NBUCK 768                // destination buckets (3 blocks/CU exactly)
#define NPB 131                  // nodes per bucket: 131*768 = 100608 >= N
#define CAPR 4944                // bucket capacity (mean 4167, +12 sigma)
#define RPT 20                   // bpull records per thread (ceil(4944/256))
#define CURSTRIDE 16             // cursor padded to 1 bucket / 64B line
#define GEMM32 ((N_NODES + 31) / 32)        // 3125 gemm blocks (512 thr)

// ---- ws layout (bytes) ----
#define OFF_CUR   0x000000u   // NBUCK*16 ints (48KB, memset 0): padded cursors
#define OFF_WSI   0x010000u   // N ints (memset 0): fixed-point wsum (2^-20)
#define OFF_DINV  0x090000u   // N floats
#define OFF_HH    0x100000u   // N*16 floats (6.4 MB)
#define OFF_GG    0x720000u   // N*16 ushorts (3.2 MB), bf16
#define OFF_CSR   0xB00000u   // NBUCK*CAPR int2 (30.4 MiB), bucket regions
#define WS_NEEDED ((size_t)0x1000000 + (size_t)N_EDGES * 8)

__device__ __forceinline__ unsigned short f2bf(float f) {
    unsigned u = __float_as_uint(f);
    unsigned r = (u + 0x7FFFu + ((u >> 16) & 1u)) >> 16;   // RNE
    return (unsigned short)r;
}
__device__ __forceinline__ float bf2f(unsigned short v) {
    return __uint_as_float((unsigned)v << 16);
}

// ============ main path ============
// R3: LDS atomics lane-serial -> 1 per edge per kernel. R4/R6: scattered
// cross-XCD stores write-amplify -> staged runs. R6-R9: bin stage is
// insensitive (73-86us across 4 designs) -> stop polishing it. R10: DELETE
// the sort stage entirely (51MB of csr rewrite+reread): bpull stages the
// bucket once in LDS, sorts INDICES (ushort perm), aggregates from LDS.

// K1: merged binning + GEMM + fixed-point weight sums.
__global__ void __launch_bounds__(512) k_binD(const int* __restrict__ row,
                                              const int* __restrict__ col,
                                              const float* __restrict__ ew,
                                              int* __restrict__ cursor,
                                              int* __restrict__ wsum_i,
                                              int2* __restrict__ csr,
                                              const float* __restrict__ x,
                                              const float* __restrict__ W,
                                              float* __restrict__ h) {
    __shared__ int2 srec[EPS];             // 25000 B (gemm: Ws aliases this)
    __shared__ unsigned char sbk[EPS];     // 3125 B
    __shared__ int lcnt[NBUCK];
    __shared__ int lpre[NBUCK];
    __shared__ int gofs[NBUCK];
    __shared__ int wtot[8];
    int tid = threadIdx.x;
    if (blockIdx.x < NSEG) {
        int e0 = blockIdx.x * EPS;
        for (int i = tid; i < NBUCK; i += 512) lcnt[i] = 0;
        __syncthreads();

        int2 rec[EPT];
        int meta[EPT];
#pragma unroll
        for (int k = 0; k < EPT; ++k) {
            int i = k * 512 + tid;
            if (k < EPT - 1 || i < EPS) {
                int e = e0 + i;
                int r = row[e];
                int c = col[e];
                float w = ew[e];
                int bk = c / NPB;
                int pos = atomicAdd(&lcnt[bk], 1);          // native, ret
                atomicAdd(&wsum_i[c], __float2int_rn(w * 1048576.0f)); // no-ret
                rec[k] = make_int2((r << 8) | (c - bk * NPB), __float_as_int(w));
                meta[k] = (bk << 16) | pos;
            }
        }
        __syncthreads();

        // 768-entry exclusive scan: 384 threads own 2 buckets each
        int v0 = 0, v1 = 0, ssum = 0;
        if (tid < 384) {
            v0 = lcnt[2 * tid];
            v1 = lcnt[2 * tid + 1];
            ssum = v0 + v1;
        }
        int inc = ssum;
#pragma unroll
        for (int off = 1; off < 64; off <<= 1) {
            int t = __shfl_up(inc, off);
            if ((tid & 63) >= off) inc += t;
        }
        if ((tid & 63) == 63 && tid < 384) wtot[tid >> 6] = inc;
        __syncthreads();
        if (tid < 384) {
            int woff = 0;
#pragma unroll
            for (int k = 0; k < 6; ++k)
                if (k < (tid >> 6)) woff += wtot[k];
            int excl = woff + inc - ssum;
            lpre[2 * tid] = excl;
            lpre[2 * tid + 1] = excl + v0;
            int b0 = 2 * tid, b1 = 2 * tid + 1;
            gofs[b0] = b0 * CAPR + atomicAdd(&cursor[b0 * CURSTRIDE], v0) - excl;
            gofs[b1] = b1 * CAPR + atomicAdd(&cursor[b1 * CURSTRIDE], v1) - (excl + v0);
        }
        __syncthreads();

        int mid1 = lpre[256];              // first slot of buckets >= 256
        int mid2 = lpre[512];              // first slot of buckets >= 512
#pragma unroll
        for (int k = 0; k < EPT; ++k) {
            int i = k * 512 + tid;
            if (k < EPT - 1 || i < EPS) {
                int m = meta[k];
                int slot = lpre[m >> 16] + (m & 0xFFFF);
                srec[slot] = rec[k];
                sbk[slot] = (unsigned char)(m >> 16);
            }
        }
        __syncthreads();

        for (int t = tid; t < EPS; t += 512) {
            int bk = sbk[t] + ((t >= mid2) ? 512 : ((t >= mid1) ? 256 : 0));
            csr[gofs[bk] + t] = srec[t];   // coalesced bucket-run writes
        }
    } else {
        float* Ws = (float*)srec;
        for (int i = tid; i < F_IN * F_OUT; i += 512) Ws[i] = W[i];
        __syncthreads();
        int n = (blockIdx.x - NSEG) * 32 + (tid >> 4);
        int j = tid & 15;
        if (n >= N_NODES) return;
        const float4* xr = (const float4*)(x + (size_t)n * F_IN);
        float acc = 0.0f;
#pragma unroll
        for (int k4 = 0; k4 < F_IN / 4; ++k4) {
            float4 xv = xr[k4];
            int k = k4 * 4;
            acc += xv.x * Ws[(k + 0) * F_OUT + j];
            acc += xv.y * Ws[(k + 1) * F_OUT + j];
            acc += xv.z * Ws[(k + 2) * F_OUT + j];
            acc += xv.w * Ws[(k + 3) * F_OUT + j];
        }
        h[(size_t)n * F_OUT + j] = acc;
    }
}

// K2: streaming — dinv = rsqrt(1 + wsum*2^-20); gb = bf16(dinv*h). (R4-proven)
__global__ void k_prep(const int* __restrict__ wsum_i, const float* __restrict__ h,
                       float* __restrict__ dinv, unsigned short* __restrict__ gb) {
    int t = blockIdx.x * 256 + threadIdx.x;     // one 4-element group
    if (t >= N_NODES * 4) return;
    int n = t >> 2;
    float d = rsqrtf(1.0f + (float)wsum_i[n] * (1.0f / 1048576.0f));
    if ((t & 3) == 0) dinv[n] = d;
    float4 hv = ((const float4*)h)[t];
    unsigned o0 = (unsigned)f2bf(d * hv.x) | ((unsigned)f2bf(d * hv.y) << 16);
    unsigned o1 = (unsigned)f2bf(d * hv.z) | ((unsigned)f2bf(d * hv.w) << 16);
    uint2 o; o.x = o0; o.y = o1;
    ((uint2*)gb)[t] = o;
}

// K3: merged sort+pull, one block per bucket. Stage bucket records in LDS
// (csr read ONCE, never rewritten), hist via 1 LDS ret-atomic/edge, scan,
// sort INDICES into ushort perm, then 16-lane register-accumulation pull
// straight from LDS. Saves sortB's 25.6MB write + 25.6MB re-read.
__global__ void __launch_bounds__(256, 3) k_bpull(const int* __restrict__ cursor,
                                                  const int2* __restrict__ csr,
                                                  const unsigned short* __restrict__ gb,
                                                  const float* __restrict__ dinv,
                                                  const float* __restrict__ bias,
                                                  float* __restrict__ out) {
    __shared__ int2 srec[CAPR];                 // 39552 B
    __shared__ unsigned short perm[CAPR];       // 9888 B
    __shared__ int cnt[256];
    __shared__ int basel[256];
    __shared__ int wtot[4];
    int tid = threadIdx.x;
    int b = blockIdx.x;
    int c0 = b * NPB;
    int rb = b * CAPR;
    int total = cursor[b * CURSTRIDE];
    if (total > CAPR) total = CAPR;             // statistically unreachable

    cnt[tid] = 0;
    __syncthreads();

    int meta[RPT];                              // (cl<<16)|pos per staged rec
#pragma unroll
    for (int k = 0; k < RPT; ++k) {
        int i = k * 256 + tid;
        if (i < total) {
            int2 rec = csr[rb + i];             // coalesced read (only csr read)
            srec[i] = rec;
            int cl = rec.x & 255;
            meta[k] = (cl << 16) | atomicAdd(&cnt[cl], 1);
        }
    }
    __syncthreads();

    int v = cnt[tid];
    int inc = v;
#pragma unroll
    for (int off = 1; off < 64; off <<= 1) {
        int t = __shfl_up(inc, off);
        if ((tid & 63) >= off) inc += t;
    }
    if ((tid & 63) == 63) wtot[tid >> 6] = inc;
    __syncthreads();
    int woff = 0;
#pragma unroll
    for (int k = 0; k < 4; ++k)
        if (k < (tid >> 6)) woff += wtot[k];
    basel[tid] = woff + inc - v;
    __syncthreads();

#pragma unroll
    for (int k = 0; k < RPT; ++k) {
        int i = k * 256 + tid;
        if (i < total) {
            int m = meta[k];
            perm[basel[m >> 16] + (m & 0xFFFF)] = (unsigned short)i;
        }
    }
    __syncthreads();

    // pull: wave per node, 16 lanes per record slot, register accumulation
    int wv = tid >> 6;
    int lane = tid & 63;
    int s = lane >> 4;
    int j = lane & 15;
    float bj = bias[j];
    for (int nn = wv; nn < NPB; nn += 4) {
        int n = c0 + nn;
        if (n >= N_NODES) break;
        int cv = cnt[nn];
        int base = basel[nn];
        float acc = 0.0f;
        for (int i = s; i < cv; i += 4) {
            int idx = perm[base + i];           // uniform per 16-group
            int2 rc = srec[idx];                // broadcast within group
            acc += __int_as_float(rc.y) * bf2f(gb[(size_t)(rc.x >> 8) * F_OUT + j]);
        }
        acc += __shfl_xor(acc, 16);
        acc += __shfl_xor(acc, 32);
        if (s == 0) {
            float d = dinv[n];
            float gs = bf2f(gb[(size_t)n * F_OUT + j]);   // self-loop term
            out[(size_t)n * F_OUT + j] = bj + d * (gs + acc);
        }
    }
}

// ============ fallback path (proven; fp32 g) ============

#define EDGE_BLOCKS_FB ((N_EDGES + 255) / 256)
#define GEMM_BLOCKS_FB ((N_NODES + 15) / 16)
__global__ void k_init_fb(float* __restrict__ deg) {
    int i = blockIdx.x * blockDim.x + threadIdx.x;
    if (i < N_NODES) deg[i] = 1.0f;
}
__global__ void k_fused_fb(const int* __restrict__ col, const float* __restrict__ ew,
                           float* __restrict__ deg, const float* __restrict__ x,
                           const float* __restrict__ W, float* __restrict__ h) {
    int b3 = blockIdx.x / 3;
    int r3 = blockIdx.x % 3;
    if (r3 < 2) {
        int e = (b3 * 2 + r3) * 256 + threadIdx.x;
        if (e < N_EDGES) atomicAdd(&deg[col[e]], ew[e]);
    } else {
        __shared__ float Ws[F_IN * F_OUT];
        int tid = threadIdx.x;
        for (int i = tid; i < F_IN * F_OUT; i += 256) Ws[i] = W[i];
        __syncthreads();
        int n = b3 * 16 + (tid >> 4);
        int j = tid & 15;
        if (n >= N_NODES) return;
        const float4* xr = (const float4*)(x + (size_t)n * F_IN);
        float acc = 0.0f;
#pragma unroll
        for (int k4 = 0; k4 < F_IN / 4; ++k4) {
            float4 xv = xr[k4];
            int k = k4 * 4;
            acc += xv.x * Ws[(k + 0) * F_OUT + j];
            acc += xv.y * Ws[(k + 1) * F_OUT + j];
            acc += xv.z * Ws[(k + 2) * F_OUT + j];
            acc += xv.w * Ws[(k + 3) * F_OUT + j];
        }
        h[(size_t)n * F_OUT + j] = acc;
    }
}
__global__ void k_final_fb(float* __restrict__ deg, const float* __restrict__ h,
                           const float* __restrict__ b, float* __restrict__ g,
                           float* __restrict__ out) {
    int i = blockIdx.x * blockDim.x + threadIdx.x;
    int n = i >> 4;
    int j = i & 15;
    if (n >= N_NODES) return;
    float d = rsqrtf(deg[n]);
    if (j == 0) deg[n] = d;
    float gg = d * h[i];
    g[i] = gg;
    out[i] = b[j] + d * gg;
}
__global__ void k_scatter_fb(const int* __restrict__ row, const int* __restrict__ col,
                             const float* __restrict__ ew, const float* __restrict__ dinv,
                             const float* __restrict__ g, float* __restrict__ out) {
    long long tid = (long long)blockIdx.x * blockDim.x + threadIdx.x;
    int e = (int)(tid >> 4);
    int j = (int)(tid & 15);
    if (e >= N_EDGES) return;
    int c = col[e];
    float norm = ew[e] * dinv[c];
    atomicAdd(&out[(size_t)c * F_OUT + j], g[(size_t)row[e] * F_OUT + j] * norm);
}

extern "C" void kernel_launch(void* const* d_in, const int* in_sizes, int n_in,
                              void* d_out, int out_size, void* d_ws, size_t ws_size,
                              hipStream_t stream) {
    const float* x  = (const float*)d_in[0];
    const int*   ei = (const int*)d_in[1];   // [2, N_EDGES] int32
    const float* ew = (const float*)d_in[2];
    const float* W  = (const float*)d_in[3];
    const float* b  = (const float*)d_in[4];
    float* out = (float*)d_out;

    const int* row = ei;            // edge_index[0] = source
    const int* col = ei + N_EDGES;  // edge_index[1] = destination

    char* ws = (char*)d_ws;
    dim3 blk(256);

    if (ws_size >= WS_NEEDED) {
        int*   cur  = (int*)(ws + OFF_CUR);
        int*   wsi  = (int*)(ws + OFF_WSI);
        float* dinv = (float*)(ws + OFF_DINV);
        float* h    = (float*)(ws + OFF_HH);
        unsigned short* gb = (unsigned short*)(ws + OFF_GG);
        int2*  csr  = (int2*)(ws + OFF_CSR);

        hipMemsetAsync(ws, 0, 0x90000, stream);     // cursors + wsum_i
        k_binD<<<NSEG + GEMM32, 512, 0, stream>>>(row, col, ew, cur, wsi, csr, x, W, h);
        k_prep<<<(N_NODES * 4 + 255) / 256, blk, 0, stream>>>(wsi, h, dinv, gb);
        k_bpull<<<NBUCK, blk, 0, stream>>>(cur, csr, gb, dinv, b, out);
    } else {
        float* deg = (float*)ws;
        float* h   = (float*)(ws + (1u << 20));
        float* g   = (float*)(ws + (8u << 20));
        k_init_fb<<<(N_NODES + 255) / 256, blk, 0, stream>>>(deg);
        k_fused_fb<<<EDGE_BLOCKS_FB + GEMM_BLOCKS_FB, blk, 0, stream>>>(col, ew, deg, x, W, h);
        k_final_fb<<<(N_NODES * F_OUT + 255) / 256, blk, 0, stream>>>(deg, h, b, g, out);
        long long total = (long long)N_EDGES * F_OUT;
        k_scatter_fb<<<(unsigned)((total + 255) / 256), blk, 0, stream>>>(row, col, ew, deg, g, out);
    }
}

// Round 11
// 229.695 us; speedup vs baseline: 1.6899x; 1.6899x over previous
//
#include <hip/hip_runtime.h>

#define N_NODES 100000
#define N_EDGES 3200000
#define F_IN 128
#define F_OUT 16

#define NSEG 512                 // binning segments
#define EPS (N_EDGES / NSEG)     // 6250 edges/segment (exact)
#define EPT 13                   // max edges per thread (ceil(6250/512))
#define NBUCK 512                // destination buckets
#define NPB 196                  // nodes per bucket: 196*512 = 100352 >= N
#define CAPR 7424                // bucket capacity (mean 6250, +15 sigma)
#define RPT 29                   // sort records per thread (ceil(7424/256))
#define GEMM32 ((N_NODES + 31) / 32)        // 3125 gemm blocks (512 thr)
#define PULL_BLOCKS 2048

// ---- ws layout (bytes) ----
#define OFF_CUR   0x000000u   // NBUCK ints: bucket fill counts (memset 0)
#define OFF_NPTR  0x010000u   // N ints: per-node run start (absolute csr idx)
#define OFF_NCNT  0x080000u   // N ints: per-node run length
#define OFF_DINV  0x0F0000u   // N floats
#define OFF_HH    0x160000u   // N*16 floats (6.4 MB)
#define OFF_GG    0x780000u   // N*16 ushorts (3.2 MB), bf16
#define OFF_CSR   0xB00000u   // NBUCK*CAPR int2 (29 MiB), bucket regions
#define WS_NEEDED ((size_t)0x1000000 + (size_t)N_EDGES * 8)

__device__ __forceinline__ unsigned short f2bf(float f) {
    unsigned u = __float_as_uint(f);
    unsigned r = (u + 0x7FFFu + ((u >> 16) & 1u)) >> 16;   // RNE
    return (unsigned short)r;
}
__device__ __forceinline__ float bf2f(unsigned short v) {
    return __uint_as_float((unsigned)v << 16);
}

// ============ main path ============
// R3: LDS atomics lane-serial -> exactly 1 per edge per kernel.
// R4/R6/R10: scattered cross-XCD stores AND scattered global atomics get
// write-amplified/serialized (R10: 3.2M global atomics = +130us, +125MB) ->
// per-edge loops touch global memory only with coalesced/region-owned ops.
// R6-R9: bin stage insensitive at 73-86us across 4 designs -> binA retained.
// R11: latency fixes only — 4-way partial sums in sortB's weight-sum,
// software prefetch in pull4's gather loop.

// K1: merged binning + GEMM.
//  blocks [0,NSEG): register-staged edges; ONE LDS ret-atomic per edge gives
//  rank AND (post-pass) count; global per-bucket reservation; direct global
//  write csr[gofs[bk]+pos]. blocks [NSEG,..): h = x@W, 32 nodes/block.
__global__ void __launch_bounds__(512) k_binA(const int* __restrict__ row,
                                              const int* __restrict__ col,
                                              const float* __restrict__ ew,
                                              int* __restrict__ cursor,
                                              int2* __restrict__ csr,
                                              const float* __restrict__ x,
                                              const float* __restrict__ W,
                                              float* __restrict__ h) {
    __shared__ int smem[2048];      // bin: lcnt[512]+gofs[512] | gemm: Ws 8KB
    int tid = threadIdx.x;
    if (blockIdx.x < NSEG) {
        int* lcnt = smem;
        int* gofs = smem + 512;
        int e0 = blockIdx.x * EPS;
        lcnt[tid] = 0;
        __syncthreads();

        int2 rec[EPT];
        int meta[EPT];
#pragma unroll
        for (int k = 0; k < EPT; ++k) {
            int i = k * 512 + tid;
            if (k < EPT - 1 || i < EPS) {
                int e = e0 + i;
                int r = row[e];
                int c = col[e];
                float w = ew[e];
                int bk = c / NPB;
                int pos = atomicAdd(&lcnt[bk], 1);          // native, ret
                rec[k] = make_int2((r << 8) | (c - bk * NPB), __float_as_int(w));
                meta[k] = (bk << 16) | pos;
            }
        }
        __syncthreads();

        int v = lcnt[tid];
        gofs[tid] = tid * CAPR + atomicAdd(&cursor[tid], v);  // global reserve
        __syncthreads();

#pragma unroll
        for (int k = 0; k < EPT; ++k) {
            int i = k * 512 + tid;
            if (k < EPT - 1 || i < EPS) {
                int m = meta[k];
                csr[gofs[m >> 16] + (m & 0xFFFF)] = rec[k];
            }
        }
    } else {
        float* Ws = (float*)smem;
        for (int i = tid; i < F_IN * F_OUT; i += 512) Ws[i] = W[i];
        __syncthreads();
        int n = (blockIdx.x - NSEG) * 32 + (tid >> 4);
        int j = tid & 15;
        if (n >= N_NODES) return;
        const float4* xr = (const float4*)(x + (size_t)n * F_IN);
        float acc = 0.0f;
#pragma unroll
        for (int k4 = 0; k4 < F_IN / 4; ++k4) {
            float4 xv = xr[k4];
            int k = k4 * 4;
            acc += xv.x * Ws[(k + 0) * F_OUT + j];
            acc += xv.y * Ws[(k + 1) * F_OUT + j];
            acc += xv.z * Ws[(k + 2) * F_OUT + j];
            acc += xv.w * Ws[(k + 3) * F_OUT + j];
        }
        h[(size_t)n * F_OUT + j] = acc;
    }
}

// K2: per-bucket counting sort, register-staged. ONE LDS ret-atomic per
// edge; sorted write DIRECT to the block's own exclusive 59KB csr region
// (single-owner lines). Weight-sum: 4-way partial sums (4 loads in flight,
// breaks the serial FP/load chain). Then dinv, gb = bf16(dinv*h).
__global__ void __launch_bounds__(256) k_sortB(const int* __restrict__ cursor,
                                               int2* __restrict__ csr,
                                               const float* __restrict__ h,
                                               float* __restrict__ dinv,
                                               unsigned short* __restrict__ gb,
                                               int* __restrict__ nodeptr,
                                               int* __restrict__ ncnt) {
    __shared__ int cnt[256];
    __shared__ int basel[256];
    __shared__ int wtot[4];
    __shared__ float dl[256];
    int tid = threadIdx.x;
    int b = blockIdx.x;
    int c0 = b * NPB;
    int rb = b * CAPR;
    int total = cursor[b];
    if (total > CAPR) total = CAPR;             // statistically unreachable

    cnt[tid] = 0;
    __syncthreads();

    int2 rec[RPT];
    int pos[RPT];
#pragma unroll
    for (int k = 0; k < RPT; ++k) {
        int i = k * 256 + tid;
        if (i < total) {
            rec[k] = csr[rb + i];               // coalesced read
            pos[k] = atomicAdd(&cnt[rec[k].x & 255], 1);
        }
    }
    __syncthreads();

    int v = cnt[tid];
    int inc = v;
#pragma unroll
    for (int off = 1; off < 64; off <<= 1) {
        int t = __shfl_up(inc, off);
        if ((tid & 63) >= off) inc += t;
    }
    if ((tid & 63) == 63) wtot[tid >> 6] = inc;
    __syncthreads();
    int woff = 0;
#pragma unroll
    for (int k = 0; k < 4; ++k)
        if (k < (tid >> 6)) woff += wtot[k];
    int excl = woff + inc - v;
    int n = c0 + tid;
    if (tid < NPB && n < N_NODES) {
        nodeptr[n] = rb + excl;
        ncnt[n] = v;
    }
    basel[tid] = excl;
    __syncthreads();

#pragma unroll
    for (int k = 0; k < RPT; ++k) {
        int i = k * 256 + tid;
        if (i < total) {
            int cl = rec[k].x & 255;
            csr[rb + basel[cl] + pos[k]] = make_int2(rec[k].x >> 8, rec[k].y);
        }
    }
    __syncthreads();   // vmcnt(0) drained before barrier -> rewrite visible

    float d = 0.0f;
    if (tid < NPB && n < N_NODES) {
        // 4 independent partial sums: 4 loads in flight instead of a serial
        // dependent chain (R11 latency fix).
        float s0 = 1.0f, s1 = 0.0f, s2 = 0.0f, s3 = 0.0f;   // 1.0 = self-loop
        const int2* run = csr + rb + excl;
        int k = 0;
        for (; k + 4 <= v; k += 4) {
            s0 += __int_as_float(run[k + 0].y);
            s1 += __int_as_float(run[k + 1].y);
            s2 += __int_as_float(run[k + 2].y);
            s3 += __int_as_float(run[k + 3].y);
        }
        for (; k < v; ++k) s0 += __int_as_float(run[k].y);
        float s = (s0 + s1) + (s2 + s3);
        d = rsqrtf(s);
        dinv[n] = d;
    }
    dl[tid] = d;
    __syncthreads();
    for (int i = tid; i < NPB * F_OUT; i += 256) {
        int idx = c0 * F_OUT + i;
        if (idx < N_NODES * F_OUT) gb[idx] = f2bf(dl[i >> 4] * h[idx]);
    }
}

// K3: pull, wave per node. Lane-per-record coalesced csr loads (512B/wave)
// with SOFTWARE PREFETCH of the next batch (R11: overlaps csr latency under
// the gb gathers), 16 per-lane feature accumulators from two dwordx4
// gathers of the L2-resident bf16 g-table, fold-reduction (lane l4 ends
// holding feature bitrev4(l4)), epilogue adds self-term + bias.
__global__ void __launch_bounds__(256) k_pull4(const int* __restrict__ nodeptr,
                                               const int* __restrict__ ncnt,
                                               const int2* __restrict__ csr,
                                               const unsigned short* __restrict__ gb,
                                               const float* __restrict__ dinv,
                                               const float* __restrict__ bias,
                                               float* __restrict__ out) {
    int wid = threadIdx.x >> 6;
    int lane = threadIdx.x & 63;
    int l4 = lane & 15;
    int fr = ((l4 & 1) << 3) | ((l4 & 2) << 1) | ((l4 & 4) >> 1) | ((l4 & 8) >> 3);
    float bj = bias[fr];
    for (int n = blockIdx.x * 4 + wid; n < N_NODES; n += PULL_BLOCKS * 4) {
        int p0 = nodeptr[n];
        int c = ncnt[n];
        float acc[16];
#pragma unroll
        for (int k = 0; k < 16; ++k) acc[k] = 0.0f;
        int2 rec = (lane < c) ? csr[p0 + lane] : make_int2(0, 0);  // prime
        for (int base = 0; base < c; base += 64) {
            int2 cur = rec;
            int ni = base + 64 + lane;
            rec = (ni < c) ? csr[p0 + ni] : make_int2(0, 0);       // prefetch
            float w = __int_as_float(cur.y);
            const uint4* gr = (const uint4*)(gb + ((size_t)cur.x << 4));
            uint4 qa = gr[0];
            uint4 qb = gr[1];
            acc[0]  += w * __uint_as_float(qa.x << 16);
            acc[1]  += w * __uint_as_float(qa.x & 0xFFFF0000u);
            acc[2]  += w * __uint_as_float(qa.y << 16);
            acc[3]  += w * __uint_as_float(qa.y & 0xFFFF0000u);
            acc[4]  += w * __uint_as_float(qa.z << 16);
            acc[5]  += w * __uint_as_float(qa.z & 0xFFFF0000u);
            acc[6]  += w * __uint_as_float(qa.w << 16);
            acc[7]  += w * __uint_as_float(qa.w & 0xFFFF0000u);
            acc[8]  += w * __uint_as_float(qb.x << 16);
            acc[9]  += w * __uint_as_float(qb.x & 0xFFFF0000u);
            acc[10] += w * __uint_as_float(qb.y << 16);
            acc[11] += w * __uint_as_float(qb.y & 0xFFFF0000u);
            acc[12] += w * __uint_as_float(qb.z << 16);
            acc[13] += w * __uint_as_float(qb.z & 0xFFFF0000u);
            acc[14] += w * __uint_as_float(qb.w << 16);
            acc[15] += w * __uint_as_float(qb.w & 0xFFFF0000u);
        }
        // fold-reduce: halve acc count per butterfly step
        bool b1 = (lane & 1) != 0;
#pragma unroll
        for (int k = 0; k < 8; ++k) {
            float keep = b1 ? acc[k + 8] : acc[k];
            float send = b1 ? acc[k] : acc[k + 8];
            acc[k] = keep + __shfl_xor(send, 1);
        }
        bool b2 = (lane & 2) != 0;
#pragma unroll
        for (int k = 0; k < 4; ++k) {
            float keep = b2 ? acc[k + 4] : acc[k];
            float send = b2 ? acc[k] : acc[k + 4];
            acc[k] = keep + __shfl_xor(send, 2);
        }
        bool b4 = (lane & 4) != 0;
#pragma unroll
        for (int k = 0; k < 2; ++k) {
            float keep = b4 ? acc[k + 2] : acc[k];
            float send = b4 ? acc[k] : acc[k + 2];
            acc[k] = keep + __shfl_xor(send, 4);
        }
        bool b8 = (lane & 8) != 0;
        {
            float keep = b8 ? acc[1] : acc[0];
            float send = b8 ? acc[0] : acc[1];
            acc[0] = keep + __shfl_xor(send, 8);
        }
        acc[0] += __shfl_xor(acc[0], 16);
        acc[0] += __shfl_xor(acc[0], 32);
        if (lane < 16) {
            float d = dinv[n];
            float gs = bf2f(gb[(size_t)n * F_OUT + fr]);
            out[(size_t)n * F_OUT + fr] = bj + d * (gs + acc[0]);
        }
    }
}

// ============ fallback path (proven; fp32 g) ============

#define EDGE_BLOCKS_FB ((N_EDGES + 255) / 256)
#define GEMM_BLOCKS_FB ((N_NODES + 15) / 16)
__global__ void k_init_fb(float* __restrict__ deg) {
    int i = blockIdx.x * blockDim.x + threadIdx.x;
    if (i < N_NODES) deg[i] = 1.0f;
}
__global__ void k_fused_fb(const int* __restrict__ col, const float* __restrict__ ew,
                           float* __restrict__ deg, const float* __restrict__ x,
                           const float* __restrict__ W, float* __restrict__ h) {
    int b3 = blockIdx.x / 3;
    int r3 = blockIdx.x % 3;
    if (r3 < 2) {
        int e = (b3 * 2 + r3) * 256 + threadIdx.x;
        if (e < N_EDGES) atomicAdd(&deg[col[e]], ew[e]);
    } else {
        __shared__ float Ws[F_IN * F_OUT];
        int tid = threadIdx.x;
        for (int i = tid; i < F_IN * F_OUT; i += 256) Ws[i] = W[i];
        __syncthreads();
        int n = b3 * 16 + (tid >> 4);
        int j = tid & 15;
        if (n >= N_NODES) return;
        const float4* xr = (const float4*)(x + (size_t)n * F_IN);
        float acc = 0.0f;
#pragma unroll
        for (int k4 = 0; k4 < F_IN / 4; ++k4) {
            float4 xv = xr[k4];
            int k = k4 * 4;
            acc += xv.x * Ws[(k + 0) * F_OUT + j];
            acc += xv.y * Ws[(k + 1) * F_OUT + j];
            acc += xv.z * Ws[(k + 2) * F_OUT + j];
            acc += xv.w * Ws[(k + 3) * F_OUT + j];
        }
        h[(size_t)n * F_OUT + j] = acc;
    }
}
__global__ void k_final_fb(float* __restrict__ deg, const float* __restrict__ h,
                           const float* __restrict__ b, float* __restrict__ g,
                           float* __restrict__ out) {
    int i = blockIdx.x * blockDim.x + threadIdx.x;
    int n = i >> 4;
    int j = i & 15;
    if (n >= N_NODES) return;
    float d = rsqrtf(deg[n]);
    if (j == 0) deg[n] = d;
    float gg = d * h[i];
    g[i] = gg;
    out[i] = b[j] + d * gg;
}
__global__ void k_scatter_fb(const int* __restrict__ row, const int* __restrict__ col,
                             const float* __restrict__ ew, const float* __restrict__ dinv,
                             const float* __restrict__ g, float* __restrict__ out) {
    long long tid = (long long)blockIdx.x * blockDim.x + threadIdx.x;
    int e = (int)(tid >> 4);
    int j = (int)(tid & 15);
    if (e >= N_EDGES) return;
    int c = col[e];
    float norm = ew[e] * dinv[c];
    atomicAdd(&out[(size_t)c * F_OUT + j], g[(size_t)row[e] * F_OUT + j] * norm);
}

extern "C" void kernel_launch(void* const* d_in, const int* in_sizes, int n_in,
                              void* d_out, int out_size, void* d_ws, size_t ws_size,
                              hipStream_t stream) {
    const float* x  = (const float*)d_in[0];
    const int*   ei = (const int*)d_in[1];   // [2, N_EDGES] int32
    const float* ew = (const float*)d_in[2];
    const float* W  = (const float*)d_in[3];
    const float* b  = (const float*)d_in[4];
    float* out = (float*)d_out;

    const int* row = ei;            // edge_index[0] = source
    const int* col = ei + N_EDGES;  // edge_index[1] = destination

    char* ws = (char*)d_ws;
    dim3 blk(256);

    if (ws_size >= WS_NEEDED) {
        int*   cur  = (int*)(ws + OFF_CUR);
        int*   nptr = (int*)(ws + OFF_NPTR);
        int*   ncnt = (int*)(ws + OFF_NCNT);
        float* dinv = (float*)(ws + OFF_DINV);
        float* h    = (float*)(ws + OFF_HH);
        unsigned short* gb = (unsigned short*)(ws + OFF_GG);
        int2*  csr  = (int2*)(ws + OFF_CSR);

        hipMemsetAsync(cur, 0, NBUCK * sizeof(int), stream);
        k_binA<<<NSEG + GEMM32, 512, 0, stream>>>(row, col, ew, cur, csr, x, W, h);
        k_sortB<<<NBUCK, blk, 0, stream>>>(cur, csr, h, dinv, gb, nptr, ncnt);
        k_pull4<<<PULL_BLOCKS, blk, 0, stream>>>(nptr, ncnt, csr, gb, dinv, b, out);
    } else {
        float* deg = (float*)ws;
        float* h   = (float*)(ws + (1u << 20));
        float* g   = (float*)(ws + (8u << 20));
        k_init_fb<<<(N_NODES + 255) / 256, blk, 0, stream>>>(deg);
        k_fused_fb<<<EDGE_BLOCKS_FB + GEMM_BLOCKS_FB, blk, 0, stream>>>(col, ew, deg, x, W, h);
        k_final_fb<<<(N_NODES * F_OUT + 255) / 256, blk, 0, stream>>>(deg, h, b, g, out);
        long long total = (long long)N_EDGES * F_OUT;
        k_scatter_fb<<<(unsigned)((total + 255) / 256), blk, 0, stream>>>(row, col, ew, deg, g, out);
    }
}

// Round 12
// 224.415 us; speedup vs baseline: 1.7297x; 1.0235x over previous
//
#include <hip/hip_runtime.h>

#define N_NODES 100000
#define N_EDGES 3200000
#define F_IN 128
#define F_OUT 16

#define NSEG 512                 // binning segments
#define EPS (N_EDGES / NSEG)     // 6250 edges/segment (exact)
#define EPT 13                   // max edges per thread (ceil(6250/512))
#define NBUCK 512                // destination buckets
#define NPB 196                  // nodes per bucket: 196*512 = 100352 >= N
#define CAPR 7424                // bucket capacity (mean 6250, +15 sigma)
#define RPT 29                   // sort records per thread (ceil(7424/256))
#define GEMM32 ((N_NODES + 31) / 32)        // 3125 gemm blocks (512 thr)
#define PULL_BLOCKS 2048

// ---- ws layout (bytes) ----
#define OFF_CUR   0x000000u   // NBUCK ints: bucket fill counts (memset 0)
#define OFF_NPTR  0x010000u   // N ints: per-node run start (absolute csr idx)
#define OFF_NCNT  0x080000u   // N ints: per-node run length
#define OFF_DINV  0x0F0000u   // N floats
#define OFF_HH    0x160000u   // N*16 floats (6.4 MB)
#define OFF_GG    0x780000u   // N*16 ushorts (3.2 MB), bf16
#define OFF_CSR   0xB00000u   // NBUCK*CAPR int2 (29 MiB), bucket regions
#define WS_NEEDED ((size_t)0x1000000 + (size_t)N_EDGES * 8)

__device__ __forceinline__ unsigned short f2bf(float f) {
    unsigned u = __float_as_uint(f);
    unsigned r = (u + 0x7FFFu + ((u >> 16) & 1u)) >> 16;   // RNE
    return (unsigned short)r;
}
__device__ __forceinline__ float bf2f(unsigned short v) {
    return __uint_as_float((unsigned)v << 16);
}

// ============ main path ============
// R3: LDS atomics lane-serial -> exactly 1 per edge per kernel.
// R4/R6/R10: scattered cross-XCD stores AND scattered global atomics get
// write-amplified/serialized -> per-edge loops touch global memory only with
// coalesced/region-owned ops. R6-R9: bin stage insensitive (73-86us over 4
// designs) -> binA retained as-is. R12: avg degree 32 = half a wave -> pull
// runs TWO nodes per wave (halves per-node gather instruction count).

// K1: merged binning + GEMM.
//  blocks [0,NSEG): register-staged edges; ONE LDS ret-atomic per edge gives
//  rank AND (post-pass) count; global per-bucket reservation; direct global
//  write csr[gofs[bk]+pos]. blocks [NSEG,..): h = x@W, 32 nodes/block.
__global__ void __launch_bounds__(512) k_binA(const int* __restrict__ row,
                                              const int* __restrict__ col,
                                              const float* __restrict__ ew,
                                              int* __restrict__ cursor,
                                              int2* __restrict__ csr,
                                              const float* __restrict__ x,
                                              const float* __restrict__ W,
                                              float* __restrict__ h) {
    __shared__ int smem[2048];      // bin: lcnt[512]+gofs[512] | gemm: Ws 8KB
    int tid = threadIdx.x;
    if (blockIdx.x < NSEG) {
        int* lcnt = smem;
        int* gofs = smem + 512;
        int e0 = blockIdx.x * EPS;
        lcnt[tid] = 0;
        __syncthreads();

        int2 rec[EPT];
        int meta[EPT];
#pragma unroll
        for (int k = 0; k < EPT; ++k) {
            int i = k * 512 + tid;
            if (k < EPT - 1 || i < EPS) {
                int e = e0 + i;
                int r = row[e];
                int c = col[e];
                float w = ew[e];
                int bk = c / NPB;
                int pos = atomicAdd(&lcnt[bk], 1);          // native, ret
                rec[k] = make_int2((r << 8) | (c - bk * NPB), __float_as_int(w));
                meta[k] = (bk << 16) | pos;
            }
        }
        __syncthreads();

        int v = lcnt[tid];
        gofs[tid] = tid * CAPR + atomicAdd(&cursor[tid], v);  // global reserve
        __syncthreads();

#pragma unroll
        for (int k = 0; k < EPT; ++k) {
            int i = k * 512 + tid;
            if (k < EPT - 1 || i < EPS) {
                int m = meta[k];
                csr[gofs[m >> 16] + (m & 0xFFFF)] = rec[k];
            }
        }
    } else {
        float* Ws = (float*)smem;
        for (int i = tid; i < F_IN * F_OUT; i += 512) Ws[i] = W[i];
        __syncthreads();
        int n = (blockIdx.x - NSEG) * 32 + (tid >> 4);
        int j = tid & 15;
        if (n >= N_NODES) return;
        const float4* xr = (const float4*)(x + (size_t)n * F_IN);
        float acc = 0.0f;
#pragma unroll
        for (int k4 = 0; k4 < F_IN / 4; ++k4) {
            float4 xv = xr[k4];
            int k = k4 * 4;
            acc += xv.x * Ws[(k + 0) * F_OUT + j];
            acc += xv.y * Ws[(k + 1) * F_OUT + j];
            acc += xv.z * Ws[(k + 2) * F_OUT + j];
            acc += xv.w * Ws[(k + 3) * F_OUT + j];
        }
        h[(size_t)n * F_OUT + j] = acc;
    }
}

// K2: per-bucket counting sort, register-staged. ONE LDS ret-atomic per
// edge; sorted write DIRECT to the block's own exclusive 59KB csr region
// (single-owner lines). Weight-sum: 4-way partial sums (4 loads in flight).
// Then dinv, gb = bf16(dinv*h).
__global__ void __launch_bounds__(256) k_sortB(const int* __restrict__ cursor,
                                               int2* __restrict__ csr,
                                               const float* __restrict__ h,
                                               float* __restrict__ dinv,
                                               unsigned short* __restrict__ gb,
                                               int* __restrict__ nodeptr,
                                               int* __restrict__ ncnt) {
    __shared__ int cnt[256];
    __shared__ int basel[256];
    __shared__ int wtot[4];
    __shared__ float dl[256];
    int tid = threadIdx.x;
    int b = blockIdx.x;
    int c0 = b * NPB;
    int rb = b * CAPR;
    int total = cursor[b];
    if (total > CAPR) total = CAPR;             // statistically unreachable

    cnt[tid] = 0;
    __syncthreads();

    int2 rec[RPT];
    int pos[RPT];
#pragma unroll
    for (int k = 0; k < RPT; ++k) {
        int i = k * 256 + tid;
        if (i < total) {
            rec[k] = csr[rb + i];               // coalesced read
            pos[k] = atomicAdd(&cnt[rec[k].x & 255], 1);
        }
    }
    __syncthreads();

    int v = cnt[tid];
    int inc = v;
#pragma unroll
    for (int off = 1; off < 64; off <<= 1) {
        int t = __shfl_up(inc, off);
        if ((tid & 63) >= off) inc += t;
    }
    if ((tid & 63) == 63) wtot[tid >> 6] = inc;
    __syncthreads();
    int woff = 0;
#pragma unroll
    for (int k = 0; k < 4; ++k)
        if (k < (tid >> 6)) woff += wtot[k];
    int excl = woff + inc - v;
    int n = c0 + tid;
    if (tid < NPB && n < N_NODES) {
        nodeptr[n] = rb + excl;
        ncnt[n] = v;
    }
    basel[tid] = excl;
    __syncthreads();

#pragma unroll
    for (int k = 0; k < RPT; ++k) {
        int i = k * 256 + tid;
        if (i < total) {
            int cl = rec[k].x & 255;
            csr[rb + basel[cl] + pos[k]] = make_int2(rec[k].x >> 8, rec[k].y);
        }
    }
    __syncthreads();   // vmcnt(0) drained before barrier -> rewrite visible

    float d = 0.0f;
    if (tid < NPB && n < N_NODES) {
        float s0 = 1.0f, s1 = 0.0f, s2 = 0.0f, s3 = 0.0f;   // 1.0 = self-loop
        const int2* run = csr + rb + excl;
        int k = 0;
        for (; k + 4 <= v; k += 4) {
            s0 += __int_as_float(run[k + 0].y);
            s1 += __int_as_float(run[k + 1].y);
            s2 += __int_as_float(run[k + 2].y);
            s3 += __int_as_float(run[k + 3].y);
        }
        for (; k < v; ++k) s0 += __int_as_float(run[k].y);
        float s = (s0 + s1) + (s2 + s3);
        d = rsqrtf(s);
        dinv[n] = d;
    }
    dl[tid] = d;
    __syncthreads();
    for (int i = tid; i < NPB * F_OUT; i += 256) {
        int idx = c0 * F_OUT + i;
        if (idx < N_NODES * F_OUT) gb[idx] = f2bf(dl[i >> 4] * h[idx]);
    }
}

// K3: pull, TWO nodes per wave (avg degree 32 = half a wave; R12).
// Lanes 0-31 own node 2q, lanes 32-63 own node 2q+1; each half runs the
// prime+prefetch record loop over its own run (stride 32). Fold-reduce masks
// 1,2,4,8,16 never cross the 32-lane boundary, so each half reduces its own
// node; lanes <16 of each half write out. Adjacent runs are contiguous in
// the bucket -> the 64-lane csr load stays ~2x256B coalesced.
__global__ void __launch_bounds__(256) k_pull5(const int* __restrict__ nodeptr,
                                               const int* __restrict__ ncnt,
                                               const int2* __restrict__ csr,
                                               const unsigned short* __restrict__ gb,
                                               const float* __restrict__ dinv,
                                               const float* __restrict__ bias,
                                               float* __restrict__ out) {
    int wid = threadIdx.x >> 6;
    int lane = threadIdx.x & 63;
    int half = lane >> 5;
    int l32 = lane & 31;
    int l4 = lane & 15;
    int fr = ((l4 & 1) << 3) | ((l4 & 2) << 1) | ((l4 & 4) >> 1) | ((l4 & 8) >> 3);
    float bj = bias[fr];
    const int NPAIR = (N_NODES + 1) / 2;
    for (int q = blockIdx.x * 4 + wid; q < NPAIR; q += PULL_BLOCKS * 4) {
        int n = q * 2 + half;
        bool valid = (n < N_NODES);
        int p0 = valid ? nodeptr[n] : 0;
        int c = valid ? ncnt[n] : 0;
        float acc[16];
#pragma unroll
        for (int k = 0; k < 16; ++k) acc[k] = 0.0f;
        int2 rec = (l32 < c) ? csr[p0 + l32] : make_int2(0, 0);    // prime
        for (int base = 0; base < c; base += 32) {
            int2 cur = rec;
            int ni = base + 32 + l32;
            rec = (ni < c) ? csr[p0 + ni] : make_int2(0, 0);       // prefetch
            float w = __int_as_float(cur.y);
            const uint4* gr = (const uint4*)(gb + ((size_t)cur.x << 4));
            uint4 qa = gr[0];
            uint4 qb = gr[1];
            acc[0]  += w * __uint_as_float(qa.x << 16);
            acc[1]  += w * __uint_as_float(qa.x & 0xFFFF0000u);
            acc[2]  += w * __uint_as_float(qa.y << 16);
            acc[3]  += w * __uint_as_float(qa.y & 0xFFFF0000u);
            acc[4]  += w * __uint_as_float(qa.z << 16);
            acc[5]  += w * __uint_as_float(qa.z & 0xFFFF0000u);
            acc[6]  += w * __uint_as_float(qa.w << 16);
            acc[7]  += w * __uint_as_float(qa.w & 0xFFFF0000u);
            acc[8]  += w * __uint_as_float(qb.x << 16);
            acc[9]  += w * __uint_as_float(qb.x & 0xFFFF0000u);
            acc[10] += w * __uint_as_float(qb.y << 16);
            acc[11] += w * __uint_as_float(qb.y & 0xFFFF0000u);
            acc[12] += w * __uint_as_float(qb.z << 16);
            acc[13] += w * __uint_as_float(qb.z & 0xFFFF0000u);
            acc[14] += w * __uint_as_float(qb.w << 16);
            acc[15] += w * __uint_as_float(qb.w & 0xFFFF0000u);
        }
        // fold-reduce within each 32-lane half
        bool b1 = (lane & 1) != 0;
#pragma unroll
        for (int k = 0; k < 8; ++k) {
            float keep = b1 ? acc[k + 8] : acc[k];
            float send = b1 ? acc[k] : acc[k + 8];
            acc[k] = keep + __shfl_xor(send, 1);
        }
        bool b2 = (lane & 2) != 0;
#pragma unroll
        for (int k = 0; k < 4; ++k) {
            float keep = b2 ? acc[k + 4] : acc[k];
            float send = b2 ? acc[k] : acc[k + 4];
            acc[k] = keep + __shfl_xor(send, 2);
        }
        bool b4 = (lane & 4) != 0;
#pragma unroll
        for (int k = 0; k < 2; ++k) {
            float keep = b4 ? acc[k + 2] : acc[k];
            float send = b4 ? acc[k] : acc[k + 2];
            acc[k] = keep + __shfl_xor(send, 4);
        }
        bool b8 = (lane & 8) != 0;
        {
            float keep = b8 ? acc[1] : acc[0];
            float send = b8 ? acc[0] : acc[1];
            acc[0] = keep + __shfl_xor(send, 8);
        }
        acc[0] += __shfl_xor(acc[0], 16);      // combine 16-groups within half
        if (l32 < 16 && valid) {
            float d = dinv[n];
            float gs = bf2f(gb[(size_t)n * F_OUT + fr]);
            out[(size_t)n * F_OUT + fr] = bj + d * (gs + acc[0]);
        }
    }
}

// ============ fallback path (proven; fp32 g) ============

#define EDGE_BLOCKS_FB ((N_EDGES + 255) / 256)
#define GEMM_BLOCKS_FB ((N_NODES + 15) / 16)
__global__ void k_init_fb(float* __restrict__ deg) {
    int i = blockIdx.x * blockDim.x + threadIdx.x;
    if (i < N_NODES) deg[i] = 1.0f;
}
__global__ void k_fused_fb(const int* __restrict__ col, const float* __restrict__ ew,
                           float* __restrict__ deg, const float* __restrict__ x,
                           const float* __restrict__ W, float* __restrict__ h) {
    int b3 = blockIdx.x / 3;
    int r3 = blockIdx.x % 3;
    if (r3 < 2) {
        int e = (b3 * 2 + r3) * 256 + threadIdx.x;
        if (e < N_EDGES) atomicAdd(&deg[col[e]], ew[e]);
    } else {
        __shared__ float Ws[F_IN * F_OUT];
        int tid = threadIdx.x;
        for (int i = tid; i < F_IN * F_OUT; i += 256) Ws[i] = W[i];
        __syncthreads();
        int n = b3 * 16 + (tid >> 4);
        int j = tid & 15;
        if (n >= N_NODES) return;
        const float4* xr = (const float4*)(x + (size_t)n * F_IN);
        float acc = 0.0f;
#pragma unroll
        for (int k4 = 0; k4 < F_IN / 4; ++k4) {
            float4 xv = xr[k4];
            int k = k4 * 4;
            acc += xv.x * Ws[(k + 0) * F_OUT + j];
            acc += xv.y * Ws[(k + 1) * F_OUT + j];
            acc += xv.z * Ws[(k + 2) * F_OUT + j];
            acc += xv.w * Ws[(k + 3) * F_OUT + j];
        }
        h[(size_t)n * F_OUT + j] = acc;
    }
}
__global__ void k_final_fb(float* __restrict__ deg, const float* __restrict__ h,
                           const float* __restrict__ b, float* __restrict__ g,
                           float* __restrict__ out) {
    int i = blockIdx.x * blockDim.x + threadIdx.x;
    int n = i >> 4;
    int j = i & 15;
    if (n >= N_NODES) return;
    float d = rsqrtf(deg[n]);
    if (j == 0) deg[n] = d;
    float gg = d * h[i];
    g[i] = gg;
    out[i] = b[j] + d * gg;
}
__global__ void k_scatter_fb(const int* __restrict__ row, const int* __restrict__ col,
                             const float* __restrict__ ew, const float* __restrict__ dinv,
                             const float* __restrict__ g, float* __restrict__ out) {
    long long tid = (long long)blockIdx.x * blockDim.x + threadIdx.x;
    int e = (int)(tid >> 4);
    int j = (int)(tid & 15);
    if (e >= N_EDGES) return;
    int c = col[e];
    float norm = ew[e] * dinv[c];
    atomicAdd(&out[(size_t)c * F_OUT + j], g[(size_t)row[e] * F_OUT + j] * norm);
}

extern "C" void kernel_launch(void* const* d_in, const int* in_sizes, int n_in,
                              void* d_out, int out_size, void* d_ws, size_t ws_size,
                              hipStream_t stream) {
    const float* x  = (const float*)d_in[0];
    const int*   ei = (const int*)d_in[1];   // [2, N_EDGES] int32
    const float* ew = (const float*)d_in[2];
    const float* W  = (const float*)d_in[3];
    const float* b  = (const float*)d_in[4];
    float* out = (float*)d_out;

    const int* row = ei;            // edge_index[0] = source
    const int* col = ei + N_EDGES;  // edge_index[1] = destination

    char* ws = (char*)d_ws;
    dim3 blk(256);

    if (ws_size >= WS_NEEDED) {
        int*   cur  = (int*)(ws + OFF_CUR);
        int*   nptr = (int*)(ws + OFF_NPTR);
        int*   ncnt = (int*)(ws + OFF_NCNT);
        float* dinv = (float*)(ws + OFF_DINV);
        float* h    = (float*)(ws + OFF_HH);
        unsigned short* gb = (unsigned short*)(ws + OFF_GG);
        int2*  csr  = (int2*)(ws + OFF_CSR);

        hipMemsetAsync(cur, 0, NBUCK * sizeof(int), stream);
        k_binA<<<NSEG + GEMM32, 512, 0, stream>>>(row, col, ew, cur, csr, x, W, h);
        k_sortB<<<NBUCK, blk, 0, stream>>>(cur, csr, h, dinv, gb, nptr, ncnt);
        k_pull5<<<PULL_BLOCKS, blk, 0, stream>>>(nptr, ncnt, csr, gb, dinv, b, out);
    } else {
        float* deg = (float*)ws;
        float* h   = (float*)(ws + (1u << 20));
        float* g   = (float*)(ws + (8u << 20));
        k_init_fb<<<(N_NODES + 255) / 256, blk, 0, stream>>>(deg);
        k_fused_fb<<<EDGE_BLOCKS_FB + GEMM_BLOCKS_FB, blk, 0, stream>>>(col, ew, deg, x, W, h);
        k_final_fb<<<(N_NODES * F_OUT + 255) / 256, blk, 0, stream>>>(deg, h, b, g, out);
        long long total = (long long)N_EDGES * F_OUT;
        k_scatter_fb<<<(unsigned)((total + 255) / 256), blk, 0, stream>>>(row, col, ew, deg, g, out);
    }
}